// Round 9
// baseline (139.889 us; speedup 1.0000x reference)
//
#include <hip/hip_runtime.h>
#include <stdint.h>

// Problem constants (reference: B=2, C=4, SPATIAL=(128,128,128), N_PTS=32, THR=0.5)
#define Bn 2
#define Cn 4
#define Sn (128 * 128 * 128)   // 2^21 voxels per (b,c)
#define NPTS 32
#define NBINS 1025             // probs in (0.5, 1] -> one binade; (bits-0x3F000000)>>13 in [0,1024]
#define THRf 0.5f
#define PB 4096                // voxels per block in the fused pass
#define BT 512                 // threads/block: 8 waves; LDS 16.4KB -> 4 blk/CU = 32 waves/CU
#define NBLK (Sn / PB)         // 512 fused blocks per batch
#define SEGCAP 128             // cand slots per (block,class); typical fill ~33
#define FCAP 2048              // LDS filtered-candidate cap in select_emit

__device__ __forceinline__ int bin_of_bits(unsigned int u) {
    return (int)((u - 0x3F000000u) >> 13);
}

// Softmax pieces for one voxel; mirrors jax.nn.softmax arithmetic exactly
// (exp(x-max), sequential sum c=0..3). Division is done by the CALLER, and only
// for prefiltered candidates: em > 0.5f*s decides em/s > 0.5 exactly (0.5f*s is
// a power-of-two scale; s >= 1 so no subnormal issues). Reference's fl(em/s) >
// 0.5 can only reject a subset of prefilter-passers; survivors re-test p > 0.5
// after the identical float division, so the accepted set is bit-identical.
__device__ __forceinline__ void softmax_parts4(float l0, float l1, float l2, float l3,
                                               int* cm_out, float* em_out, float* s_out) {
    float m = fmaxf(fmaxf(l0, l1), fmaxf(l2, l3));
    float e0 = expf(l0 - m);
    float e1 = expf(l1 - m);
    float e2 = expf(l2 - m);
    float e3 = expf(l3 - m);
    float s = ((e0 + e1) + e2) + e3;
    float em = e0; int cm = 0;
    if (e1 > em) { em = e1; cm = 1; }
    if (e2 > em) { em = e2; cm = 2; }
    if (e3 > em) { em = e3; cm = 3; }
    *cm_out = cm;   // only the argmax class can exceed p=0.5 (probs sum to 1)
    *em_out = em;
    *s_out = s;
}

// Fused single-read pass, register-resident candidates, segment output.
// R8->R9 changes: (1) full-precision divide only for the ~45% prefiltered
// candidates; (2) cand output is a fixed segment per (block,class) with an
// unconditional count word -> no global counters to zero -> the memset
// dispatch is gone; (3) done[] zeroed here (kernel-boundary visibility).
__global__ __launch_bounds__(BT) void fused_kernel(const float* __restrict__ logits,
                                                   unsigned int* __restrict__ cnt2,
                                                   uint2* __restrict__ cand,
                                                   unsigned int* __restrict__ done) {
    __shared__ unsigned int lh[Cn * NBINS];   // 16.4 KB per-class local radix hist
    __shared__ unsigned int lcut[Cn], cls_cnt[Cn], cls_pos[Cn];
    const int b = blockIdx.y;
    const int t = threadIdx.x;
    const int lane = t & 63;
    for (int j = t; j < Cn * NBINS; j += BT) lh[j] = 0u;
    if (t < Cn) { lcut[t] = 0u; cls_cnt[t] = 0u; cls_pos[t] = 0u; }
    if (blockIdx.x == 0 && b == 0 && t < Bn) done[t] = 0u;  // visible to select_emit
    __syncthreads();

    // phase 1: stream voxels (float4 x 4 class streams); results stay in registers
    const float* base = logits + (size_t)b * Cn * Sn;
    const float4* s0 = (const float4*)base;
    const float4* s1 = (const float4*)(base + Sn);
    const float4* s2 = (const float4*)(base + 2 * Sn);
    const float4* s3 = (const float4*)(base + 3 * Sn);
    const int qs = blockIdx.x * (PB / 4);
    unsigned int pk[PB / BT];   // 8 packed results per thread; (p_off<<2)|class, 0=invalid
    #pragma unroll
    for (int it = 0; it < PB / 4 / BT; ++it) {   // 2 iterations
        int q = qs + it * BT + t;
        float4 v0 = s0[q], v1 = s1[q], v2 = s2[q], v3 = s3[q];
        const float* a0 = &v0.x; const float* a1 = &v1.x;
        const float* a2 = &v2.x; const float* a3 = &v3.x;
        #pragma unroll
        for (int k = 0; k < 4; ++k) {
            int cm; float em, s;
            softmax_parts4(a0[k], a1[k], a2[k], a3[k], &cm, &em, &s);
            unsigned int pv = 0u;
            if (em > 0.5f * s) {                 // exact prefilter: em/s > 0.5 in reals
                float p = em / s;                // identical float division to reference
                if (p > THRf) {                  // identical final test
                    unsigned int off = __float_as_uint(p) - 0x3F000000u;  // 1..0x800000
                    atomicAdd(&lh[cm * NBINS + (int)(off >> 13)], 1u);    // no-return ds_add
                    pv = (off << 2) | (unsigned int)cm;
                }
            }
            pk[it * 4 + k] = pv;
        }
    }
    __syncthreads();

    // phase 2: wave w (w<4) computes local cutoff for class w (64 lanes x 17 bins >= 1025).
    // Entries below the local cutoff have >=32 strictly-greater local entries ->
    // global rank >= 32 -> safe to drop. Union over blocks is a superset of top-32.
    {
        const int wave = t >> 6;
        if (wave < Cn) {
            const unsigned int* h = &lh[wave * NBINS];
            const int lo = lane * 17;
            unsigned int cs = 0;
            #pragma unroll
            for (int k = 0; k < 17; ++k) {
                int bin = lo + k;
                if (bin < NBINS) cs += h[bin];
            }
            unsigned int S = cs;  // inclusive suffix sum over lanes [lane..63]
            #pragma unroll
            for (int off = 1; off < 64; off <<= 1) {
                unsigned int v = __shfl_down(S, off, 64);
                if (lane + off < 64) S += v;
            }
            unsigned int suf = S - cs;
            if (S >= NPTS && suf < NPTS) {   // exactly one lane (when total >= 32)
                unsigned int acc = suf;
                int hi = min(lo + 16, NBINS - 1);
                for (int bin = hi; bin >= lo; --bin) {
                    acc += h[bin];
                    if (acc >= NPTS) {
                        lcut[wave] = (unsigned int)bin;
                        cls_cnt[wave] = acc;
                        break;
                    }
                }
            }
            if (lane == 0 && S < NPTS) cls_cnt[wave] = S;  // total<32: lcut=0, emit all
        }
    }
    __syncthreads();

    // phase 3: emit survivors (~130/block) into this block's own segments;
    // LDS returning atomic only (~2 per wave-step). No global atomics at all.
    #pragma unroll
    for (int j = 0; j < PB / BT; ++j) {
        unsigned int pv = pk[j];
        if (pv != 0u) {
            unsigned int cm = pv & 3u;
            if ((pv >> 15) >= lcut[cm]) {   // pv>>15 == p_off>>13 == bin
                unsigned int pos = atomicAdd(&cls_pos[cm], 1u);
                if (pos < SEGCAP) {
                    int it = j >> 2, k = j & 3;
                    unsigned int idx = (unsigned int)((qs + it * BT + t) * 4 + k);
                    cand[((size_t)(b * Cn + cm) * NBLK + blockIdx.x) * SEGCAP + pos] =
                        make_uint2(0x3F000000u + (pv >> 2), idx);
                }
            }
        }
    }
    __syncthreads();
    if (t < Cn)  // unconditional count word — nothing needs pre-zeroing
        cnt2[(size_t)(b * Cn + t) * NBLK + blockIdx.x] = min(cls_pos[t], (unsigned int)SEGCAP);
}

// Exact top-32 per (b,c) (one 1024-thread block per (b,c)) from the segmented
// superset, then the LAST finishing block of each batch (done-counter +
// threadfence) performs the cross-class compaction/emit.
// Correctness: bins strictly above the superset-derived cutoff are complete in
// the superset, so ranking within the filtered set is exact for the top-32;
// validn = min(total,32) is exact (entries are only dropped when >=32
// locally-greater entries exist).
__global__ __launch_bounds__(1024) void select_emit(const unsigned int* __restrict__ cnt2,
                                                    const uint2* __restrict__ cand,
                                                    unsigned int* __restrict__ validn,
                                                    uint2* __restrict__ topk,
                                                    unsigned int* __restrict__ done,
                                                    int* __restrict__ out) {
    __shared__ unsigned int lh[NBINS];
    __shared__ unsigned int scnt[NBLK];
    __shared__ uint2 fbuf[FCAP];
    __shared__ unsigned int s_n, s_m, s_T, s_old;
    const int bc = blockIdx.x, t = threadIdx.x;
    const int b = bc >> 2;
    for (int j = t; j < NBINS; j += 1024) lh[j] = 0u;
    if (t == 0) { s_n = 0u; s_m = 0u; s_T = 0u; }
    __syncthreads();
    for (int j = t; j < NBLK; j += 1024) {
        unsigned int c = cnt2[(size_t)bc * NBLK + j];
        scnt[j] = c;
        if (c) atomicAdd(&s_n, c);
    }
    __syncthreads();
    const uint2* seg = cand + (size_t)bc * NBLK * SEGCAP;
    for (int j = t; j < NBLK * SEGCAP; j += 1024) {   // 64 iters; ~17 valid
        if ((unsigned int)(j & (SEGCAP - 1)) < scnt[j >> 7])
            atomicAdd(&lh[bin_of_bits(seg[j].x)], 1u);
    }
    __syncthreads();
    if (t < 64) {  // wave 0: exact global cutoff scan (64 lanes x 17 bins >= 1025)
        const int lane = t;
        const int lo = lane * 17;
        unsigned int cs = 0;
        #pragma unroll
        for (int k = 0; k < 17; ++k) {
            int bin = lo + k;
            if (bin < NBINS) cs += lh[bin];
        }
        unsigned int S = cs;
        #pragma unroll
        for (int off = 1; off < 64; off <<= 1) {
            unsigned int v = __shfl_down(S, off, 64);
            if (lane + off < 64) S += v;
        }
        unsigned int suf = S - cs;
        if (S >= NPTS && suf < NPTS) {
            unsigned int acc = suf;
            int hi = min(lo + 16, NBINS - 1);
            for (int bin = hi; bin >= lo; --bin) {
                acc += lh[bin];
                if (acc >= NPTS) { s_T = (unsigned int)bin; break; }
            }
        }
    }
    __syncthreads();
    const unsigned int T = s_T;
    for (int j = t; j < NBLK * SEGCAP; j += 1024) {
        if ((unsigned int)(j & (SEGCAP - 1)) < scnt[j >> 7]) {
            uint2 e = seg[j];   // L2-hot re-read
            if ((unsigned int)bin_of_bits(e.x) >= T) {
                unsigned int pos = atomicAdd(&s_m, 1u);   // ~40 total, cheap
                if (pos < FCAP) fbuf[pos] = e;
            }
        }
    }
    __syncthreads();
    const int m = min((int)s_m, FCAP);
    const int vn = min((int)s_n, NPTS);
    if (t == 0) validn[bc] = (unsigned int)vn;
    for (int i = t; i < m; i += 1024) {   // exact rank, jax tie-break (lower idx wins)
        uint2 e = fbuf[i];
        int rank = 0;
        for (int j = 0; j < m; ++j) {
            uint2 o = fbuf[j];
            rank += (int)((o.x > e.x) || (o.x == e.x && o.y < e.y));
        }
        if (rank < vn) topk[bc * NPTS + rank] = e;
    }

    // epilogue: last finishing block of this batch emits
    __threadfence();
    __syncthreads();
    if (t == 0) s_old = atomicAdd(&done[b], 1u);
    __syncthreads();
    if (s_old == 3u) {
        __threadfence();  // acquire: see other blocks' topk/validn
        __shared__ int pre[Cn + 1];
        if (t == 0) {
            int acc = 0;
            for (int oc = 0; oc < Cn; ++oc) {
                pre[oc] = acc;
                acc += (int)validn[b * Cn + ((oc + 1) & 3)];  // order [1,2,3,0]
            }
            pre[Cn] = acc;
        }
        __syncthreads();
        if (t < Cn * NPTS) {  // 128 output slots for batch b
            const int j = t;
            int label = -1, z = 0, y = 0, x = 0;
            if (j < pre[Cn]) {
                int oc = 0;
                while (j >= pre[oc + 1]) ++oc;
                int c = (oc + 1) & 3;
                int r = j - pre[oc];
                uint2 e = topk[(b * Cn + c) * NPTS + r];
                int idx = (int)e.y;
                z = idx >> 14;          // idx / (128*128)
                y = (idx >> 7) & 127;   // (idx / 128) % 128
                x = idx & 127;          // idx % 128
                label = c;
            }
            int* coords = out;                       // 2*128*3 = 768 ints
            int* labels = out + Bn * Cn * NPTS * 3;  // then 2*128 = 256 ints
            int bo = b * Cn * NPTS + j;
            coords[bo * 3 + 0] = z;
            coords[bo * 3 + 1] = y;
            coords[bo * 3 + 2] = x;
            labels[bo] = label;
        }
    }
}

extern "C" void kernel_launch(void* const* d_in, const int* in_sizes, int n_in,
                              void* d_out, int out_size, void* d_ws, size_t ws_size,
                              hipStream_t stream) {
    const float* logits = (const float*)d_in[0];
    int* out = (int*)d_out;

    // Workspace layout (no pre-zeroing needed anywhere):
    unsigned int* cnt2 = (unsigned int*)d_ws;            // 8*512 u32 = 16 KB @0
    unsigned int* validn = cnt2 + Bn * Cn * NBLK;        // 8 u32
    unsigned int* done = validn + Bn * Cn;               // 2 u32
    uint2* topk = (uint2*)(done + Bn + 6);               // pad to 8-byte alignment
    uint2* cand = topk + Bn * Cn * NPTS;                 // 8*512*128 uint2 = 4 MB

    dim3 grid(NBLK, Bn);   // (512, 2) = 1024 blocks, fully co-resident at 4 blk/CU
    fused_kernel<<<grid, BT, 0, stream>>>(logits, cnt2, cand, done);
    select_emit<<<Bn * Cn, 1024, 0, stream>>>(cnt2, cand, validn, topk, done, out);
}

// Round 10
// 122.665 us; speedup vs baseline: 1.1404x; 1.1404x over previous
//
#include <hip/hip_runtime.h>
#include <stdint.h>

// Problem constants (reference: B=2, C=4, SPATIAL=(128,128,128), N_PTS=32, THR=0.5)
#define Bn 2
#define Cn 4
#define Sn (128 * 128 * 128)   // 2^21 voxels per (b,c)
#define NPTS 32
#define NBINS 1025             // probs in (0.5, 1] -> one binade; (bits-0x3F000000)>>13 in [0,1024]
#define THRf 0.5f
#define PB 4096                // voxels per block in the fused pass
#define BT 512                 // threads/block: 8 waves; LDS 16.4KB -> 4 blk/CU = 32 waves/CU
#define NBLK (Sn / PB)         // 512 fused blocks per batch
#define FCAP 2048              // LDS filtered-candidate cap in select_emit

__device__ __forceinline__ int bin_of_bits(unsigned int u) {
    return (int)((u - 0x3F000000u) >> 13);
}

// Softmax pieces for one voxel; mirrors jax.nn.softmax arithmetic exactly
// (exp(x-max), sequential sum c=0..3). Division only for prefiltered candidates:
// em > 0.5f*s decides em/s > 0.5 exactly (power-of-two scale), and survivors
// re-test p > 0.5 after the identical float division -> accept set is
// bit-identical to the reference (established R9, passed absmax 0).
__device__ __forceinline__ void softmax_parts4(float l0, float l1, float l2, float l3,
                                               int* cm_out, float* em_out, float* s_out) {
    float m = fmaxf(fmaxf(l0, l1), fmaxf(l2, l3));
    float e0 = expf(l0 - m);
    float e1 = expf(l1 - m);
    float e2 = expf(l2 - m);
    float e3 = expf(l3 - m);
    float s = ((e0 + e1) + e2) + e3;
    float em = e0; int cm = 0;
    if (e1 > em) { em = e1; cm = 1; }
    if (e2 > em) { em = e2; cm = 2; }
    if (e3 > em) { em = e3; cm = 3; }
    *cm_out = cm;   // only the argmax class can exceed p=0.5 (probs sum to 1)
    *em_out = em;
    *s_out = s;
}

// Fused single-read pass (R10 = R8 compact-cand + R9 divide prefilter + global
// superset histogram so select_emit needs only ONE scan).
// R9 lesson: segmented cand made select scan 65536 mostly-dead slots twice at
// 1.2% occupancy -> 52-58 us. Compact cand via per-(block,class) global
// reservation (~4k atomics total) is the right trade.
__global__ __launch_bounds__(BT) void fused_kernel(const float* __restrict__ logits,
                                                   unsigned int* __restrict__ cnt,
                                                   unsigned int* __restrict__ ghist,
                                                   uint2* __restrict__ cand,
                                                   int cap) {
    __shared__ unsigned int lh[Cn * NBINS];   // 16.4 KB per-class local radix hist
    __shared__ unsigned int lcut[Cn], cls_cnt[Cn], cls_base[Cn], cls_pos[Cn];
    const int b = blockIdx.y;
    const int t = threadIdx.x;
    const int lane = t & 63;
    for (int j = t; j < Cn * NBINS; j += BT) lh[j] = 0u;
    if (t < Cn) { lcut[t] = 0u; cls_cnt[t] = 0u; cls_pos[t] = 0u; }
    __syncthreads();

    // phase 1: stream voxels (float4 x 4 class streams); results stay in registers
    const float* base = logits + (size_t)b * Cn * Sn;
    const float4* s0 = (const float4*)base;
    const float4* s1 = (const float4*)(base + Sn);
    const float4* s2 = (const float4*)(base + 2 * Sn);
    const float4* s3 = (const float4*)(base + 3 * Sn);
    const int qs = blockIdx.x * (PB / 4);
    unsigned int pk[PB / BT];   // 8 packed results per thread; (p_off<<2)|class, 0=invalid
    #pragma unroll
    for (int it = 0; it < PB / 4 / BT; ++it) {   // 2 iterations
        int q = qs + it * BT + t;
        float4 v0 = s0[q], v1 = s1[q], v2 = s2[q], v3 = s3[q];
        const float* a0 = &v0.x; const float* a1 = &v1.x;
        const float* a2 = &v2.x; const float* a3 = &v3.x;
        #pragma unroll
        for (int k = 0; k < 4; ++k) {
            int cm; float em, s;
            softmax_parts4(a0[k], a1[k], a2[k], a3[k], &cm, &em, &s);
            unsigned int pv = 0u;
            if (em > 0.5f * s) {                 // exact prefilter: em/s > 0.5 in reals
                float p = em / s;                // identical float division to reference
                if (p > THRf) {                  // identical final test
                    unsigned int off = __float_as_uint(p) - 0x3F000000u;  // 1..0x800000
                    atomicAdd(&lh[cm * NBINS + (int)(off >> 13)], 1u);    // no-return ds_add
                    pv = (off << 2) | (unsigned int)cm;
                }
            }
            pk[it * 4 + k] = pv;
        }
    }
    __syncthreads();

    // phase 2: wave w (w<4) computes local cutoff for class w (64 lanes x 17 bins >= 1025).
    // Entries below the local cutoff have >=32 strictly-greater local entries ->
    // global rank >= 32 -> safe to drop. Union over blocks is a superset of top-32.
    {
        const int wave = t >> 6;
        if (wave < Cn) {
            const unsigned int* h = &lh[wave * NBINS];
            const int lo = lane * 17;
            unsigned int cs = 0;
            #pragma unroll
            for (int k = 0; k < 17; ++k) {
                int bin = lo + k;
                if (bin < NBINS) cs += h[bin];
            }
            unsigned int S = cs;  // inclusive suffix sum over lanes [lane..63]
            #pragma unroll
            for (int off = 1; off < 64; off <<= 1) {
                unsigned int v = __shfl_down(S, off, 64);
                if (lane + off < 64) S += v;
            }
            unsigned int suf = S - cs;
            if (S >= NPTS && suf < NPTS) {   // exactly one lane (when total >= 32)
                unsigned int acc = suf;
                int hi = min(lo + 16, NBINS - 1);
                for (int bin = hi; bin >= lo; --bin) {
                    acc += h[bin];
                    if (acc >= NPTS) {
                        lcut[wave] = (unsigned int)bin;
                        cls_cnt[wave] = acc;
                        break;
                    }
                }
            }
            if (lane == 0 && S < NPTS) cls_cnt[wave] = S;  // total<32: lcut=0, emit all
        }
    }
    __syncthreads();

    // phase 2b: merge surviving bins (bin >= lcut, ~140 nonzero) into the global
    // per-(b,c) superset histogram. Scattered atomics over 4100 addresses — cheap
    // (R2's hist merge). The superset hist yields the exact global cutoff T:
    // bins strictly above T are complete in the superset.
    for (int j = t; j < Cn * NBINS; j += BT) {
        unsigned int v = lh[j];
        if (v) {
            int c = j / NBINS, bin = j - c * NBINS;
            if ((unsigned int)bin >= lcut[c])
                atomicAdd(&ghist[(size_t)(b * Cn + c) * NBINS + bin], v);
        }
    }

    // reservation: one global atomic per (block, class)
    if (t < Cn && cls_cnt[t] > 0)
        cls_base[t] = atomicAdd(&cnt[b * Cn + t], cls_cnt[t]);
    __syncthreads();

    // phase 3: emit survivors (~130/block) from registers into compact cand;
    // LDS returning atomic only (~2 per wave-step).
    #pragma unroll
    for (int j = 0; j < PB / BT; ++j) {
        unsigned int pv = pk[j];
        if (pv != 0u) {
            unsigned int cm = pv & 3u;
            if ((pv >> 15) >= lcut[cm]) {   // pv>>15 == p_off>>13 == bin
                unsigned int pos = cls_base[cm] + atomicAdd(&cls_pos[cm], 1u);
                if (pos < (unsigned int)cap) {
                    int it = j >> 2, k = j & 3;
                    unsigned int idx = (unsigned int)((qs + it * BT + t) * 4 + k);
                    cand[(size_t)(b * Cn + cm) * cap + pos] =
                        make_uint2(0x3F000000u + (pv >> 2), idx);
                }
            }
        }
    }
}

// Exact top-32 per (b,c) (one 1024-thread block per (b,c)): T from the
// precomputed superset hist (no LDS-hist scan), ONE filtered scan of compact
// cand, O(m^2) exact rank; then the last finishing block of each batch emits.
// validn = min(n,32) is exact: if total>=32 the superset has >=32, else lcut=0
// everywhere and n == total.
__global__ __launch_bounds__(1024) void select_emit(const unsigned int* __restrict__ cnt,
                                                    const unsigned int* __restrict__ ghist,
                                                    const uint2* __restrict__ cand,
                                                    int cap,
                                                    unsigned int* __restrict__ validn,
                                                    uint2* __restrict__ topk,
                                                    unsigned int* __restrict__ done,
                                                    int* __restrict__ out) {
    __shared__ unsigned int lh[NBINS];
    __shared__ uint2 fbuf[FCAP];
    __shared__ unsigned int s_m, s_T, s_old;
    const int bc = blockIdx.x, t = threadIdx.x;
    const int b = bc >> 2;
    const int n = min((int)cnt[bc], cap);
    for (int j = t; j < NBINS; j += 1024) lh[j] = ghist[(size_t)bc * NBINS + j];
    if (t == 0) { s_m = 0u; s_T = 0u; }
    __syncthreads();
    if (t < 64) {  // wave 0: exact global cutoff scan (64 lanes x 17 bins >= 1025)
        const int lane = t;
        const int lo = lane * 17;
        unsigned int cs = 0;
        #pragma unroll
        for (int k = 0; k < 17; ++k) {
            int bin = lo + k;
            if (bin < NBINS) cs += lh[bin];
        }
        unsigned int S = cs;
        #pragma unroll
        for (int off = 1; off < 64; off <<= 1) {
            unsigned int v = __shfl_down(S, off, 64);
            if (lane + off < 64) S += v;
        }
        unsigned int suf = S - cs;
        if (S >= NPTS && suf < NPTS) {
            unsigned int acc = suf;
            int hi = min(lo + 16, NBINS - 1);
            for (int bin = hi; bin >= lo; --bin) {
                acc += lh[bin];
                if (acc >= NPTS) { s_T = (unsigned int)bin; break; }
            }
        }
    }
    __syncthreads();
    const unsigned int T = s_T;
    const uint2* src = cand + (size_t)bc * cap;
    for (int j = t; j < n; j += 1024) {   // ~17 dense iterations, the only cand scan
        uint2 e = src[j];
        if ((unsigned int)bin_of_bits(e.x) >= T) {
            unsigned int pos = atomicAdd(&s_m, 1u);   // ~40 total, cheap
            if (pos < FCAP) fbuf[pos] = e;
        }
    }
    __syncthreads();
    const int m = min((int)s_m, FCAP);
    const int vn = min(n, NPTS);
    if (t == 0) validn[bc] = (unsigned int)vn;
    for (int i = t; i < m; i += 1024) {   // exact rank, jax tie-break (lower idx wins)
        uint2 e = fbuf[i];
        int rank = 0;
        for (int j = 0; j < m; ++j) {
            uint2 o = fbuf[j];
            rank += (int)((o.x > e.x) || (o.x == e.x && o.y < e.y));
        }
        if (rank < vn) topk[bc * NPTS + rank] = e;
    }

    // epilogue: last finishing block of this batch emits
    __threadfence();
    __syncthreads();
    if (t == 0) s_old = atomicAdd(&done[b], 1u);
    __syncthreads();
    if (s_old == 3u) {
        __threadfence();  // acquire: see other blocks' topk/validn
        __shared__ int pre[Cn + 1];
        if (t == 0) {
            int acc = 0;
            for (int oc = 0; oc < Cn; ++oc) {
                pre[oc] = acc;
                acc += (int)validn[b * Cn + ((oc + 1) & 3)];  // order [1,2,3,0]
            }
            pre[Cn] = acc;
        }
        __syncthreads();
        if (t < Cn * NPTS) {  // 128 output slots for batch b
            const int j = t;
            int label = -1, z = 0, y = 0, x = 0;
            if (j < pre[Cn]) {
                int oc = 0;
                while (j >= pre[oc + 1]) ++oc;
                int c = (oc + 1) & 3;
                int r = j - pre[oc];
                uint2 e = topk[(b * Cn + c) * NPTS + r];
                int idx = (int)e.y;
                z = idx >> 14;          // idx / (128*128)
                y = (idx >> 7) & 127;   // (idx / 128) % 128
                x = idx & 127;          // idx % 128
                label = c;
            }
            int* coords = out;                       // 2*128*3 = 768 ints
            int* labels = out + Bn * Cn * NPTS * 3;  // then 2*128 = 256 ints
            int bo = b * Cn * NPTS + j;
            coords[bo * 3 + 0] = z;
            coords[bo * 3 + 1] = y;
            coords[bo * 3 + 2] = x;
            labels[bo] = label;
        }
    }
}

extern "C" void kernel_launch(void* const* d_in, const int* in_sizes, int n_in,
                              void* d_out, int out_size, void* d_ws, size_t ws_size,
                              hipStream_t stream) {
    const float* logits = (const float*)d_in[0];
    int* out = (int*)d_out;

    // Workspace layout; [cnt | done | ghist] is one contiguous zeroed region.
    unsigned int* cnt = (unsigned int*)d_ws;             // 8 u32
    unsigned int* done = cnt + Bn * Cn;                  // 2 u32
    unsigned int* ghist = done + Bn;                     // 8*1025 u32 = 32.8 KB
    unsigned int* validn = ghist + Bn * Cn * NBINS;      // 8 u32
    uint2* topk = (uint2*)(validn + Bn * Cn + 6);        // pad to 8-byte alignment
    uint2* cand = topk + Bn * Cn * NPTS;                 // 8 * cap uint2
    size_t fixed = (size_t)((char*)cand - (char*)d_ws);
    int cap = (int)((ws_size - fixed) / (Bn * Cn * sizeof(uint2)));
    if (cap > (1 << 18)) cap = 1 << 18;   // 256k entries/bc >> the ~18k expected
    if (cap < 4096) cap = 4096;

    // Zero cnt + done + ghist (32.9 KB, one dispatch)
    hipMemsetAsync(cnt, 0, (size_t)(Bn * Cn + Bn + Bn * Cn * NBINS) * sizeof(unsigned int),
                   stream);

    dim3 grid(NBLK, Bn);   // (512, 2) = 1024 blocks, fully co-resident at 4 blk/CU
    fused_kernel<<<grid, BT, 0, stream>>>(logits, cnt, ghist, cand, cap);
    select_emit<<<Bn * Cn, 1024, 0, stream>>>(cnt, ghist, cand, cap, validn, topk, done, out);
}

// Round 11
// 120.784 us; speedup vs baseline: 1.1582x; 1.0156x over previous
//
#include <hip/hip_runtime.h>
#include <stdint.h>

// Problem constants (reference: B=2, C=4, SPATIAL=(128,128,128), N_PTS=32, THR=0.5)
#define Bn 2
#define Cn 4
#define Sn (128 * 128 * 128)   // 2^21 voxels per (b,c)
#define NPTS 32
#define NBINS 1025             // probs in (0.5, 1] -> one binade; (bits-0x3F000000)>>13 in [0,1024]
#define THRf 0.5f
#define PB 4096                // voxels per block in the fused pass
#define BT 512                 // threads/block: 8 waves
#define FCAP 2048              // LDS filtered-candidate cap in select_emit

__device__ __forceinline__ int bin_of_bits(unsigned int u) {
    return (int)((u - 0x3F000000u) >> 13);
}

// Softmax over the 4 classes at one voxel; mirrors jax.nn.softmax exactly
// (exp(x-max)/sum, sequential sum c=0..3). Only the argmax class can exceed 0.5.
__device__ __forceinline__ void softmax_argmax4(float l0, float l1, float l2, float l3,
                                                int* cm_out, float* p_out) {
    float m = fmaxf(fmaxf(l0, l1), fmaxf(l2, l3));
    float e0 = expf(l0 - m);
    float e1 = expf(l1 - m);
    float e2 = expf(l2 - m);
    float e3 = expf(l3 - m);
    float s = ((e0 + e1) + e2) + e3;
    float em = e0; int cm = 0;
    if (e1 > em) { em = e1; cm = 1; }
    if (e2 > em) { em = e2; cm = 2; }
    if (e3 > em) { em = e3; cm = 3; }
    *cm_out = cm;
    *p_out = em / s;
}

// Fused single-read pass — R8 champion structure (register-resident candidates,
// compact cand via per-(block,class) global reservation), with ONE change:
// __launch_bounds__(512, 8) forces VGPR <= 64. R7-R10 counters showed 68 VGPR,
// which caps occupancy at ~3 blocks/CU (24 waves) despite LDS allowing 4; at
// <=64 VGPR we get 4 blocks/CU = 32 waves/CU for better latency hiding of the
// streaming loads (R6 profile: VALUBusy 38%, hbm 13% -> latency-stalled).
__global__ __launch_bounds__(BT, 8) void fused_kernel(const float* __restrict__ logits,
                                                      unsigned int* __restrict__ cnt,
                                                      uint2* __restrict__ cand,
                                                      int cap) {
    __shared__ unsigned int lh[Cn * NBINS];   // 16.4 KB per-class local radix hist
    __shared__ unsigned int lcut[Cn], cls_cnt[Cn], cls_base[Cn], cls_pos[Cn];
    const int b = blockIdx.y;
    const int t = threadIdx.x;
    const int lane = t & 63;
    for (int j = t; j < Cn * NBINS; j += BT) lh[j] = 0u;
    if (t < Cn) { lcut[t] = 0u; cls_cnt[t] = 0u; cls_pos[t] = 0u; }
    __syncthreads();

    // phase 1: stream voxels (float4 x 4 class streams); results stay in registers
    const float* base = logits + (size_t)b * Cn * Sn;
    const float4* s0 = (const float4*)base;
    const float4* s1 = (const float4*)(base + Sn);
    const float4* s2 = (const float4*)(base + 2 * Sn);
    const float4* s3 = (const float4*)(base + 3 * Sn);
    const int qs = blockIdx.x * (PB / 4);
    unsigned int pk[PB / BT];   // 8 packed results per thread; (p_off<<2)|class, 0=invalid
    #pragma unroll
    for (int it = 0; it < PB / 4 / BT; ++it) {   // 2 iterations
        int q = qs + it * BT + t;
        float4 v0 = s0[q], v1 = s1[q], v2 = s2[q], v3 = s3[q];
        const float* a0 = &v0.x; const float* a1 = &v1.x;
        const float* a2 = &v2.x; const float* a3 = &v3.x;
        #pragma unroll
        for (int k = 0; k < 4; ++k) {
            int cm; float p;
            softmax_argmax4(a0[k], a1[k], a2[k], a3[k], &cm, &p);
            unsigned int pv = 0u;
            if (p > THRf) {
                unsigned int off = __float_as_uint(p) - 0x3F000000u;  // 1..0x800000
                atomicAdd(&lh[cm * NBINS + (int)(off >> 13)], 1u);    // no-return ds_add
                pv = (off << 2) | (unsigned int)cm;                   // 26 bits, nonzero
            }
            pk[it * 4 + k] = pv;
        }
    }
    __syncthreads();

    // phase 2: wave w (w<4) computes local cutoff for class w (64 lanes x 17 bins >= 1025).
    // Entries below the local cutoff have >=32 strictly-greater local entries ->
    // global rank >= 32 -> safe to drop. Union over blocks is a superset of top-32.
    // The break-time acc = count of entries in bins >= lcut = exact emit count.
    {
        const int wave = t >> 6;
        if (wave < Cn) {
            const unsigned int* h = &lh[wave * NBINS];
            const int lo = lane * 17;
            unsigned int cs = 0;
            #pragma unroll
            for (int k = 0; k < 17; ++k) {
                int bin = lo + k;
                if (bin < NBINS) cs += h[bin];
            }
            unsigned int S = cs;  // inclusive suffix sum over lanes [lane..63]
            #pragma unroll
            for (int off = 1; off < 64; off <<= 1) {
                unsigned int v = __shfl_down(S, off, 64);
                if (lane + off < 64) S += v;
            }
            unsigned int suf = S - cs;
            if (S >= NPTS && suf < NPTS) {   // exactly one lane (when total >= 32)
                unsigned int acc = suf;
                int hi = min(lo + 16, NBINS - 1);
                for (int bin = hi; bin >= lo; --bin) {
                    acc += h[bin];
                    if (acc >= NPTS) {
                        lcut[wave] = (unsigned int)bin;
                        cls_cnt[wave] = acc;
                        break;
                    }
                }
            }
            if (lane == 0 && S < NPTS) cls_cnt[wave] = S;  // total<32: lcut=0, emit all
        }
    }
    __syncthreads();

    // reservation: one global atomic per (block, class)
    if (t < Cn && cls_cnt[t] > 0)
        cls_base[t] = atomicAdd(&cnt[b * Cn + t], cls_cnt[t]);
    __syncthreads();

    // phase 3: emit survivors straight from registers (~130/block total);
    // plain returning LDS atomic (~2 per wave-step — negligible serialization).
    #pragma unroll
    for (int j = 0; j < PB / BT; ++j) {
        unsigned int pv = pk[j];
        if (pv != 0u) {
            unsigned int cm = pv & 3u;
            if ((pv >> 15) >= lcut[cm]) {   // pv>>15 == p_off>>13 == bin
                unsigned int pos = cls_base[cm] + atomicAdd(&cls_pos[cm], 1u);
                if (pos < (unsigned int)cap) {
                    int it = j >> 2, k = j & 3;
                    unsigned int idx = (unsigned int)((qs + it * BT + t) * 4 + k);
                    cand[(size_t)(b * Cn + cm) * cap + pos] =
                        make_uint2(0x3F000000u + (pv >> 2), idx);
                }
            }
        }
    }
}

// Exact top-32 per (b,c) (one 1024-thread block per (b,c)), then the LAST
// finishing block of each batch (device done-counter + threadfence) performs the
// cross-class compaction/emit.
// Correctness: bins strictly above the superset-derived cutoff are complete in
// the superset (every such entry has global rank < 32, and all rank<32 entries
// survive every block's local cutoff), so ranking within the filtered set is
// exact for the top-32. validn = min(n,32) is exact.
__global__ __launch_bounds__(1024) void select_emit(const unsigned int* __restrict__ cnt,
                                                    const uint2* __restrict__ cand,
                                                    int cap,
                                                    unsigned int* __restrict__ validn,
                                                    uint2* __restrict__ topk,
                                                    unsigned int* __restrict__ done,
                                                    int* __restrict__ out) {
    __shared__ unsigned int lh[NBINS];
    __shared__ uint2 fbuf[FCAP];
    __shared__ unsigned int s_m, s_T, s_old;
    const int bc = blockIdx.x, t = threadIdx.x;
    const int b = bc >> 2;
    const int n = min((int)cnt[bc], cap);
    for (int j = t; j < NBINS; j += 1024) lh[j] = 0u;
    if (t == 0) { s_m = 0u; s_T = 0u; }
    __syncthreads();
    const uint2* src = cand + (size_t)bc * cap;
    for (int j = t; j < n; j += 1024)
        atomicAdd(&lh[bin_of_bits(src[j].x)], 1u);
    __syncthreads();
    if (t < 64) {  // wave 0: exact global cutoff scan (64 lanes x 17 bins >= 1025)
        const int lane = t;
        const int lo = lane * 17;
        unsigned int cs = 0;
        #pragma unroll
        for (int k = 0; k < 17; ++k) {
            int bin = lo + k;
            if (bin < NBINS) cs += lh[bin];
        }
        unsigned int S = cs;
        #pragma unroll
        for (int off = 1; off < 64; off <<= 1) {
            unsigned int v = __shfl_down(S, off, 64);
            if (lane + off < 64) S += v;
        }
        unsigned int suf = S - cs;
        if (S >= NPTS && suf < NPTS) {
            unsigned int acc = suf;
            int hi = min(lo + 16, NBINS - 1);
            for (int bin = hi; bin >= lo; --bin) {
                acc += lh[bin];
                if (acc >= NPTS) { s_T = (unsigned int)bin; break; }
            }
        }
    }
    __syncthreads();
    const unsigned int T = s_T;
    for (int j = t; j < n; j += 1024) {
        uint2 e = src[j];   // L2-hot re-read
        if ((unsigned int)bin_of_bits(e.x) >= T) {
            unsigned int pos = atomicAdd(&s_m, 1u);   // ~40 total, cheap
            if (pos < FCAP) fbuf[pos] = e;
        }
    }
    __syncthreads();
    const int m = min((int)s_m, FCAP);
    const int vn = min(n, NPTS);
    if (t == 0) validn[bc] = (unsigned int)vn;
    for (int i = t; i < m; i += 1024) {   // exact rank, jax tie-break (lower idx wins)
        uint2 e = fbuf[i];
        int rank = 0;
        for (int j = 0; j < m; ++j) {
            uint2 o = fbuf[j];
            rank += (int)((o.x > e.x) || (o.x == e.x && o.y < e.y));
        }
        if (rank < vn) topk[bc * NPTS + rank] = e;
    }

    // epilogue: last finishing block of this batch emits
    __threadfence();
    __syncthreads();
    if (t == 0) s_old = atomicAdd(&done[b], 1u);
    __syncthreads();
    if (s_old == 3u) {
        __threadfence();  // acquire: see other blocks' topk/validn
        __shared__ int pre[Cn + 1];
        if (t == 0) {
            int acc = 0;
            for (int oc = 0; oc < Cn; ++oc) {
                pre[oc] = acc;
                acc += (int)validn[b * Cn + ((oc + 1) & 3)];  // order [1,2,3,0]
            }
            pre[Cn] = acc;
        }
        __syncthreads();
        if (t < Cn * NPTS) {  // 128 output slots for batch b
            const int j = t;
            int label = -1, z = 0, y = 0, x = 0;
            if (j < pre[Cn]) {
                int oc = 0;
                while (j >= pre[oc + 1]) ++oc;
                int c = (oc + 1) & 3;
                int r = j - pre[oc];
                uint2 e = topk[(b * Cn + c) * NPTS + r];
                int idx = (int)e.y;
                z = idx >> 14;          // idx / (128*128)
                y = (idx >> 7) & 127;   // (idx / 128) % 128
                x = idx & 127;          // idx % 128
                label = c;
            }
            int* coords = out;                       // 2*128*3 = 768 ints
            int* labels = out + Bn * Cn * NPTS * 3;  // then 2*128 = 256 ints
            int bo = b * Cn * NPTS + j;
            coords[bo * 3 + 0] = z;
            coords[bo * 3 + 1] = y;
            coords[bo * 3 + 2] = x;
            labels[bo] = label;
        }
    }
}

extern "C" void kernel_launch(void* const* d_in, const int* in_sizes, int n_in,
                              void* d_out, int out_size, void* d_ws, size_t ws_size,
                              hipStream_t stream) {
    const float* logits = (const float*)d_in[0];
    int* out = (int*)d_out;

    // Workspace layout
    unsigned int* cnt = (unsigned int*)d_ws;             // 8 u32  @0
    unsigned int* done = cnt + Bn * Cn;                  // 2 u32  @32
    unsigned int* validn = done + Bn;                    // 8 u32  @40
    uint2* topk = (uint2*)(validn + Bn * Cn);            // 8*32 uint2 @72 (8-aligned)
    uint2* cand = topk + Bn * Cn * NPTS;                 // 8 * cap uint2
    size_t fixed = (size_t)((char*)cand - (char*)d_ws);
    int cap = (int)((ws_size - fixed) / (Bn * Cn * sizeof(uint2)));
    if (cap > (1 << 18)) cap = 1 << 18;   // 256k entries/bc >> the ~18k expected
    if (cap < 4096) cap = 4096;

    // Zero cnt (8) + done (2) counters only (40 B, one dispatch)
    hipMemsetAsync(cnt, 0, (Bn * Cn + Bn) * sizeof(unsigned int), stream);

    dim3 grid(Sn / PB, Bn);   // (512, 2) = 1024 blocks, fully co-resident at 4 blk/CU
    fused_kernel<<<grid, BT, 0, stream>>>(logits, cnt, cand, cap);
    select_emit<<<Bn * Cn, 1024, 0, stream>>>(cnt, cand, cap, validn, topk, done, out);
}